// Round 1
// baseline (66.702 us; speedup 1.0000x reference)
//
#include <hip/hip_runtime.h>
#include <hip/hip_bf16.h>
#include <stdint.h>

// Problem constants (AutoregressiveDense: B=8192, D=1024, STRIDE=16, OUT=64, L=64)
#define BROWS 8192
#define DDIM  1024
#define LDIM  64
#define ODIM  64
#define NDIM  4096          // L*O — also the flat bias index == output column
#define KSTRIDE 16

typedef __attribute__((ext_vector_type(8))) short bf16x8;           // MFMA A/B frag (4 VGPRs)
typedef __attribute__((ext_vector_type(4))) float f32x4;            // MFMA C/D frag
typedef __attribute__((ext_vector_type(8))) unsigned short u16x8;   // 16B bf16 store

static __device__ __forceinline__ unsigned short f2bf(float f) {
    // round-to-nearest-even f32 -> bf16 (inputs are finite randoms; no NaN handling needed)
    union { float f; uint32_t u; } v; v.f = f;
    uint32_t r = 0x7FFFu + ((v.u >> 16) & 1u);
    return (unsigned short)((v.u + r) >> 16);
}

static __device__ __forceinline__ void async16(const void* g, void* l) {
    // direct global->LDS, 16B per lane; LDS dest is wave-uniform base + lane*16
    __builtin_amdgcn_global_load_lds(
        (const __attribute__((address_space(1))) void*)g,
        (__attribute__((address_space(3))) void*)l, 16, 0, 0);
}

// ---------- prep 1: x f32 -> bf16, 8 elems/thread ----------
__global__ __launch_bounds__(256) void cvt_x_kernel(const float* __restrict__ x,
                                                    unsigned short* __restrict__ xb) {
    int i = blockIdx.x * 256 + threadIdx.x;
    const float4* xf = reinterpret_cast<const float4*>(x);
    float4 v0 = xf[2 * i];
    float4 v1 = xf[2 * i + 1];
    u16x8 r;
    r[0] = f2bf(v0.x); r[1] = f2bf(v0.y); r[2] = f2bf(v0.z); r[3] = f2bf(v0.w);
    r[4] = f2bf(v1.x); r[5] = f2bf(v1.y); r[6] = f2bf(v1.z); r[7] = f2bf(v1.w);
    reinterpret_cast<u16x8*>(xb)[i] = r;
}

// ---------- prep 2: W [L][D][O] f32 -> masked bf16 W' [N=L*64+o][K=d] (B^T layout) ----------
// One block per (layer l, 64-wide d-chunk). LDS transpose, mask d >= l*16 to zero.
__global__ __launch_bounds__(256) void prep_w_kernel(const float* __restrict__ W,
                                                     unsigned short* __restrict__ wbt) {
    __shared__ float tile[64][65];
    const int l  = blockIdx.x >> 4;
    const int d0 = (blockIdx.x & 15) << 6;
    const int t  = threadIdx.x;
    {   // coalesced load of W[l][d0+dd][o] (contiguous in o)
        const int dd = t >> 2;
        const int o4 = (t & 3) << 4;
        const float* src = W + ((size_t)((l << 10) + d0 + dd) << 6) + o4;
        #pragma unroll
        for (int j = 0; j < 4; ++j) {
            float4 v = reinterpret_cast<const float4*>(src)[j];
            tile[dd][o4 + 4 * j + 0] = v.x;
            tile[dd][o4 + 4 * j + 1] = v.y;
            tile[dd][o4 + 4 * j + 2] = v.z;
            tile[dd][o4 + 4 * j + 3] = v.w;
        }
    }
    __syncthreads();
    {   // write W'[(l*64+o)][d0+dloc .. +31] as two 16B bf16 stores, masked
        const int o    = t >> 2;
        const int dloc = (t & 3) << 4;
        const int kmax = l * KSTRIDE;
        unsigned short* dst = wbt + ((size_t)((l << 6) + o) << 10) + d0 + dloc;
        u16x8 r0, r1;
        #pragma unroll
        for (int j = 0; j < 8; ++j) {
            int da = d0 + dloc + j;
            int db = da + 8;
            r0[j] = (da < kmax) ? f2bf(tile[dloc + j][o])     : (unsigned short)0;
            r1[j] = (db < kmax) ? f2bf(tile[dloc + 8 + j][o]) : (unsigned short)0;
        }
        *reinterpret_cast<u16x8*>(dst)     = r0;
        *reinterpret_cast<u16x8*>(dst + 8) = r1;
    }
}

// ---------- main GEMM: 128x128 tile, BK=32, 4 waves (2x2), m97 2-barrier structure ----------
// A = xb [M=8192][K=1024] bf16 row-major; B^T = wbt [N=4096][K=1024] bf16 row-major.
// N-tile bn covers layers {2bn, 2bn+1} -> K loop only to ceil((2bn+1)*16/32) tiles.
__global__ __launch_bounds__(256, 2) void ar_gemm_kernel(
        const unsigned short* __restrict__ xb,
        const unsigned short* __restrict__ wbt,
        const float* __restrict__ bias,
        float* __restrict__ out) {
    __shared__ unsigned short As[128 * 32];   // [row][k] rows of 64B, linear (matches gload_lds)
    __shared__ unsigned short Bs[128 * 32];   // [col][k]

    const int bm   = blockIdx.x & 63;
    const int bn   = 31 - (blockIdx.x >> 6);  // heavy K-loops dispatch first (tail balance)
    const int tid  = threadIdx.x;
    const int lane = tid & 63;
    const int wave = tid >> 6;
    const int wr   = wave >> 1;               // 2x2 wave grid, each wave owns 64x64
    const int wc   = wave & 1;

    const int nkt = ((2 * bn + 1) * KSTRIDE + 31) >> 5;   // 1..32 K-tiles of 32

    // staging: each wave fills 2x 1KB chunks of As and Bs; lane order == linear LDS order
    const int rc = lane >> 2;            // row within a 16-row chunk
    const int cb = (lane & 3) << 4;      // byte col within the 64B row
    const char* gA0 = (const char*)xb  + ((size_t)(bm * 128 + (2 * wave + 0) * 16 + rc) * 2048) + cb;
    const char* gA1 = (const char*)xb  + ((size_t)(bm * 128 + (2 * wave + 1) * 16 + rc) * 2048) + cb;
    const char* gB0 = (const char*)wbt + ((size_t)(bn * 128 + (2 * wave + 0) * 16 + rc) * 2048) + cb;
    const char* gB1 = (const char*)wbt + ((size_t)(bn * 128 + (2 * wave + 1) * 16 + rc) * 2048) + cb;
    char* lA0 = (char*)As + (2 * wave + 0) * 1024;
    char* lA1 = (char*)As + (2 * wave + 1) * 1024;
    char* lB0 = (char*)Bs + (2 * wave + 0) * 1024;
    char* lB1 = (char*)Bs + (2 * wave + 1) * 1024;

    // fragment read offsets (bytes): row = (lane&15), k-halves by lane>>4
    const int aoff = ((wr << 6) + (lane & 15)) * 64 + ((lane >> 4) << 4);
    const int boff = ((wc << 6) + (lane & 15)) * 64 + ((lane >> 4) << 4);

    f32x4 acc[4][4];
    #pragma unroll
    for (int m = 0; m < 4; ++m)
        #pragma unroll
        for (int n = 0; n < 4; ++n)
            acc[m][n] = (f32x4)(0.f);

    for (int kt = 0; kt < nkt; ++kt) {
        const int kb = kt << 6;          // byte offset along K
        async16(gA0 + kb, lA0);
        async16(gA1 + kb, lA1);
        async16(gB0 + kb, lB0);
        async16(gB1 + kb, lB1);
        __syncthreads();                 // drains vmcnt before s_barrier (compiler-inserted)
        bf16x8 a[4], b[4];
        #pragma unroll
        for (int m = 0; m < 4; ++m)
            a[m] = *reinterpret_cast<const bf16x8*>((const char*)As + aoff + m * 1024);
        #pragma unroll
        for (int n = 0; n < 4; ++n)
            b[n] = *reinterpret_cast<const bf16x8*>((const char*)Bs + boff + n * 1024);
        #pragma unroll
        for (int m = 0; m < 4; ++m)
            #pragma unroll
            for (int n = 0; n < 4; ++n)
                acc[m][n] = __builtin_amdgcn_mfma_f32_16x16x32_bf16(a[m], b[n], acc[m][n], 0, 0, 0);
        __syncthreads();
    }

    // epilogue: C/D layout col=lane&15, row=(lane>>4)*4+j (m89/m91-verified); add bias in f32
    const int crow = (bm << 7) + (wr << 6) + ((lane >> 4) << 2);
    const int ccol = (bn << 7) + (wc << 6) + (lane & 15);
    float bv[4];
    #pragma unroll
    for (int n = 0; n < 4; ++n) bv[n] = bias[ccol + n * 16];
    #pragma unroll
    for (int m = 0; m < 4; ++m)
        #pragma unroll
        for (int n = 0; n < 4; ++n)
            #pragma unroll
            for (int j = 0; j < 4; ++j)
                out[(size_t)(crow + m * 16 + j) * NDIM + ccol + n * 16] = acc[m][n][j] + bv[n];
}

// ---------- fallback (only if workspace is too small): naive f32, correct but slow ----------
__global__ __launch_bounds__(256) void naive_kernel(const float* __restrict__ x,
                                                    const float* __restrict__ W,
                                                    const float* __restrict__ bias,
                                                    float* __restrict__ out) {
    size_t idx = (size_t)blockIdx.x * 256 + threadIdx.x;
    if (idx >= (size_t)BROWS * NDIM) return;
    int m = (int)(idx >> 12);
    int n = (int)(idx & 4095);
    int l = n >> 6;
    int o = n & 63;
    int kmax = l * KSTRIDE;
    float s = bias[n];
    const float* xr = x + (size_t)m * DDIM;
    const float* wp = W + ((size_t)l << 16) + o;
    for (int d = 0; d < kmax; ++d) s += xr[d] * wp[(size_t)d << 6];
    out[idx] = s;
}

extern "C" void kernel_launch(void* const* d_in, const int* in_sizes, int n_in,
                              void* d_out, int out_size, void* d_ws, size_t ws_size,
                              hipStream_t stream) {
    const float* x = (const float*)d_in[0];
    const float* W = (const float*)d_in[1];
    const float* b = (const float*)d_in[2];
    float* out = (float*)d_out;

    const size_t need = ((size_t)BROWS * DDIM + (size_t)NDIM * DDIM) * sizeof(unsigned short); // 25.2 MB
    if (ws_size < need) {
        int total = BROWS * NDIM;
        naive_kernel<<<(total + 255) / 256, 256, 0, stream>>>(x, W, b, out);
        return;
    }
    unsigned short* xbuf = (unsigned short*)d_ws;                  // bf16 x   [8192][1024]
    unsigned short* wbt  = xbuf + (size_t)BROWS * DDIM;            // bf16 W'  [4096][1024]

    cvt_x_kernel<<<(BROWS * DDIM) / (256 * 8), 256, 0, stream>>>(x, xbuf);
    prep_w_kernel<<<LDIM * 16, 256, 0, stream>>>(W, wbt);
    ar_gemm_kernel<<<64 * 32, 256, 0, stream>>>(xbuf, wbt, b, out);
}